// Round 9
// baseline (658.035 us; speedup 1.0000x reference)
//
#include <hip/hip_runtime.h>
#include <math.h>

#define H 512
#define W 512
#define PLANE (H*W)       // 262144
#define PLANE4 (PLANE/4)  // 65536

typedef float v2f __attribute__((ext_vector_type(2)));
typedef unsigned int uint;
typedef unsigned short ushort;

__device__ __forceinline__ float bflo(uint u){ return __uint_as_float(u<<16); }
__device__ __forceinline__ float bfhi(uint u){ return __uint_as_float(u & 0xFFFF0000u); }
__device__ __forceinline__ uint bfpack(float f0, float f1){
  uint a = __float_as_uint(f0), b = __float_as_uint(f1);
  return ((a + 0x8000u) >> 16) | ((b + 0x8000u) & 0xFFFF0000u);
}
__device__ __forceinline__ v2f mkv2(float a, float b){ v2f r; r.x=a; r.y=b; return r; }

// ---- unpack one NHWC row window of 4 pixels (XB even) into P[pixel][ch] ----
#define UNPACK_ROW(P, TL, S, ROWIDX, XB) { \
  uint4 U0 = *(const uint4*)&(TL)[(((ROWIDX))*(S)+(XB))*4]; \
  uint4 U1 = *(const uint4*)&(TL)[(((ROWIDX))*(S)+(XB)+2)*4]; \
  P[0][0]=bflo(U0.x); P[0][1]=bfhi(U0.x); P[0][2]=bflo(U0.y); P[0][3]=bfhi(U0.y); \
  P[1][0]=bflo(U0.z); P[1][1]=bfhi(U0.z); P[1][2]=bflo(U0.w); P[1][3]=bfhi(U0.w); \
  P[2][0]=bflo(U1.x); P[2][1]=bfhi(U1.x); P[2][2]=bflo(U1.y); P[2][3]=bfhi(U1.y); \
  P[3][0]=bflo(U1.z); P[3][1]=bfhi(U1.z); P[3][2]=bflo(U1.w); P[3][3]=bfhi(U1.w); }

// XB odd: pixels XB..XB+3 via three aligned uint4 (XB-1 even)
#define UNPACK_ROW_ODD(P, TL, S, ROWIDX, XB) { \
  uint4 U0 = *(const uint4*)&(TL)[(((ROWIDX))*(S)+(XB)-1)*4]; \
  uint4 U1 = *(const uint4*)&(TL)[(((ROWIDX))*(S)+(XB)+1)*4]; \
  uint4 U2 = *(const uint4*)&(TL)[(((ROWIDX))*(S)+(XB)+3)*4]; \
  P[0][0]=bflo(U0.z); P[0][1]=bfhi(U0.z); P[0][2]=bflo(U0.w); P[0][3]=bfhi(U0.w); \
  P[1][0]=bflo(U1.x); P[1][1]=bfhi(U1.x); P[1][2]=bflo(U1.y); P[1][3]=bfhi(U1.y); \
  P[2][0]=bflo(U1.z); P[2][1]=bfhi(U1.z); P[2][2]=bflo(U1.w); P[2][3]=bfhi(U1.w); \
  P[3][0]=bflo(U2.x); P[3][1]=bfhi(U2.x); P[3][2]=bflo(U2.y); P[3][3]=bfhi(U2.y); }

// one dy slice, 4 ci x 4 co, packed pairs. RL=top rows, RH=bottom rows.
#define DY4(RL, RH, Wb, INC, CIB, DYI) { \
  _Pragma("unroll") \
  for (int ci=0;ci<4;++ci){ \
    v2f A0=mkv2(RL[0][ci],RL[1][ci]), M0=mkv2(RL[1][ci],RL[2][ci]), B0=mkv2(RL[2][ci],RL[3][ci]); \
    v2f A1=mkv2(RH[0][ci],RH[1][ci]), M1=mkv2(RH[1][ci],RH[2][ci]), B1=mkv2(RH[2][ci],RH[3][ci]); \
    _Pragma("unroll") \
    for (int co=0;co<4;++co){ \
      const float* wp = (Wb) + ((co*(INC))+(CIB)+ci)*9 + (DYI)*3; \
      float w0=wp[0], w1=wp[1], w2=wp[2]; \
      acc0[co]+=A0*w0; acc0[co]+=M0*w1; acc0[co]+=B0*w2; \
      acc1[co]+=A1*w0; acc1[co]+=M1*w1; acc1[co]+=B1*w2; \
    } } }

#define ACC4_NHWC(TL, S, Wb, INC, CIB, YB, XB, ODDF) { \
  float r0_[4][4], r1_[4][4], r2_[4][4], r3_[4][4]; \
  if (ODDF){ UNPACK_ROW_ODD(r0_,TL,S,(YB)+0,XB) UNPACK_ROW_ODD(r1_,TL,S,(YB)+1,XB) } \
  else     { UNPACK_ROW(r0_,TL,S,(YB)+0,XB)     UNPACK_ROW(r1_,TL,S,(YB)+1,XB) } \
  DY4(r0_, r1_, Wb, INC, CIB, 0) \
  if (ODDF){ UNPACK_ROW_ODD(r2_,TL,S,(YB)+2,XB) } else { UNPACK_ROW(r2_,TL,S,(YB)+2,XB) } \
  DY4(r1_, r2_, Wb, INC, CIB, 1) \
  if (ODDF){ UNPACK_ROW_ODD(r3_,TL,S,(YB)+3,XB) } else { UNPACK_ROW(r3_,TL,S,(YB)+3,XB) } \
  DY4(r2_, r3_, Wb, INC, CIB, 2) }

// single-output-channel (c7)
#define DY1(RL, RH, Wb, CIB, DYI) { \
  _Pragma("unroll") \
  for (int ci=0;ci<4;++ci){ \
    v2f A0=mkv2(RL[0][ci],RL[1][ci]), M0=mkv2(RL[1][ci],RL[2][ci]), B0=mkv2(RL[2][ci],RL[3][ci]); \
    v2f A1=mkv2(RH[0][ci],RH[1][ci]), M1=mkv2(RH[1][ci],RH[2][ci]), B1=mkv2(RH[2][ci],RH[3][ci]); \
    const float* wp=(Wb)+((CIB)+ci)*9+(DYI)*3; \
    float w0=wp[0],w1=wp[1],w2=wp[2]; \
    s0+=A0*w0; s0+=M0*w1; s0+=B0*w2; \
    s1+=A1*w0; s1+=M1*w1; s1+=B1*w2; } }

#define ACC1_NHWC(TL, S, Wb, CIB, YB, XB, ODDF) { \
  float r0_[4][4], r1_[4][4], r2_[4][4], r3_[4][4]; \
  if (ODDF){ UNPACK_ROW_ODD(r0_,TL,S,(YB)+0,XB) UNPACK_ROW_ODD(r1_,TL,S,(YB)+1,XB) } \
  else     { UNPACK_ROW(r0_,TL,S,(YB)+0,XB)     UNPACK_ROW(r1_,TL,S,(YB)+1,XB) } \
  DY1(r0_,r1_,Wb,CIB,0) \
  if (ODDF){ UNPACK_ROW_ODD(r2_,TL,S,(YB)+2,XB) } else { UNPACK_ROW(r2_,TL,S,(YB)+2,XB) } \
  DY1(r1_,r2_,Wb,CIB,1) \
  if (ODDF){ UNPACK_ROW_ODD(r3_,TL,S,(YB)+3,XB) } else { UNPACK_ROW(r3_,TL,S,(YB)+3,XB) } \
  DY1(r2_,r3_,Wb,CIB,2) }

// scalar-plane (v) -> 4 co (c1); XB even, stride S ushorts
template<int S>
__device__ __forceinline__ void accp4sc(const ushort* __restrict__ pl,
    const float* __restrict__ w, int YB, int XB, v2f* acc0, v2f* acc1)
{
  v2f A[4], Mv[4], Bv[4];
  #pragma unroll
  for (int r=0;r<4;++r){
    const ushort* rp = pl + (YB+r)*S + XB;
    uint u0 = *(const uint*)rp;
    uint u1 = *(const uint*)(rp+2);
    float q0=bflo(u0), q1=bfhi(u0), q2=bflo(u1), q3=bfhi(u1);
    A[r]=mkv2(q0,q1); Mv[r]=mkv2(q1,q2); Bv[r]=mkv2(q2,q3);
  }
  #pragma unroll
  for (int dy=0; dy<3; ++dy){
    #pragma unroll
    for (int co=0; co<4; ++co){
      float w0=w[co*9+dy*3+0], w1=w[co*9+dy*3+1], w2=w[co*9+dy*3+2];
      acc0[co] += A[dy]*w0;   acc0[co] += Mv[dy]*w1;   acc0[co] += Bv[dy]*w2;
      acc1[co] += A[dy+1]*w0; acc1[co] += Mv[dy+1]*w1; acc1[co] += Bv[dy+1]*w2;
    }
  }
}

// pack quad accumulators (masked relu) into two NHWC row uint4s
#define PACK_ROWS(RL4, RH4, M00, M01, M10, M11) \
  uint4 RL4, RH4; { \
    float v00[4],v01[4],v10[4],v11[4]; \
    _Pragma("unroll") \
    for (int co=0;co<4;++co){ \
      v00[co]=(M00)?fmaxf(acc0[co].x,0.f):0.f; \
      v01[co]=(M01)?fmaxf(acc0[co].y,0.f):0.f; \
      v10[co]=(M10)?fmaxf(acc1[co].x,0.f):0.f; \
      v11[co]=(M11)?fmaxf(acc1[co].y,0.f):0.f; } \
    RL4.x=bfpack(v00[0],v00[1]); RL4.y=bfpack(v00[2],v00[3]); \
    RL4.z=bfpack(v01[0],v01[1]); RL4.w=bfpack(v01[2],v01[3]); \
    RH4.x=bfpack(v10[0],v10[1]); RH4.y=bfpack(v10[2],v10[3]); \
    RH4.z=bfpack(v11[0],v11[1]); RH4.w=bfpack(v11[2],v11[3]); }

// phase epilogue: mask, relu, pack, store to NHWC LDS tile (stride S)
#define STORE_TILE(TL, S, GOFF) { \
    bool okr0=(unsigned)(gy0+(GOFF)+y0  )<512u; \
    bool okr1=(unsigned)(gy0+(GOFF)+y0+1)<512u; \
    bool okc0=(unsigned)(gx0+(GOFF)+x0  )<512u; \
    bool okc1=(unsigned)(gx0+(GOFF)+x0+1)<512u; \
    PACK_ROWS(rowlo, rowhi, okr0&okc0, okr0&okc1, okr1&okc0, okr1&okc1) \
    *(uint4*)&(TL)[(y0*(S)+x0)*4]=rowlo; \
    *(uint4*)&(TL)[((y0+1)*(S)+x0)*4]=rowhi; }

// ============ fused conv chain: v->x1->x2->x3->x4->x5->x6->v_r, one WG per 32x32 tile ============
// LDS: vb 4232 + t1 15488 + t2 14112 + t3 12800 + t4 11552 + t5 10368 + t6 9248 = 77800 B -> 2 WG/CU
__launch_bounds__(512,4)
__global__ void k_megaconv(const float* __restrict__ xg,
    const float* __restrict__ c1w, const float* __restrict__ c1b,
    const float* __restrict__ c2w, const float* __restrict__ c2b,
    const float* __restrict__ c3w, const float* __restrict__ c3b,
    const float* __restrict__ c4w, const float* __restrict__ c4b,
    const float* __restrict__ c5w, const float* __restrict__ c5b,
    const float* __restrict__ c6w, const float* __restrict__ c6b,
    const float* __restrict__ c7w, const float* __restrict__ c7b,
    float* __restrict__ vr)
{
  __shared__ __align__(16) ushort vb[46*46];
  __shared__ __align__(16) ushort t1[44*44*4];
  __shared__ __align__(16) ushort t2[42*42*4];
  __shared__ __align__(16) ushort t3[40*40*4];
  __shared__ __align__(16) ushort t4[38*38*4];
  __shared__ __align__(16) ushort t5[36*36*4];
  __shared__ __align__(16) ushort t6[34*34*4];
  int wg=blockIdx.x, b=wg>>8, t=wg&255, ty=t>>4, tx=t&15;
  int gy0=ty*32, gx0=tx*32, tid=threadIdx.x;
  const float* xp = xg + (size_t)b*3*PLANE;

  // stage v window (origin gy0-7, gx0-7), 46x46, zero outside image
  for (int i=tid;i<46*46;i+=512){
    int rr=i/46, cc=i-rr*46;
    int gy=gy0-7+rr, gx=gx0-7+cc;
    float val=0.f;
    if (((unsigned)gy<512u)&((unsigned)gx<512u)){
      int off=gy*W+gx;
      val=(xp[off]+xp[PLANE+off]+xp[2*PLANE+off])*(1.f/3.f);
    }
    vb[i]=(ushort)((__float_as_uint(val)+0x8000u)>>16);
  }
  __syncthreads();

  // c1: vb(46) -> t1(44), out origin gy0-6
  if (tid < 484){
    int qy=tid/22, qx=tid-qy*22, y0=2*qy, x0=2*qx;
    v2f acc0[4], acc1[4];
    #pragma unroll
    for (int co=0;co<4;++co){ float bv=c1b[co]; acc0[co]=mkv2(bv,bv); acc1[co]=acc0[co]; }
    accp4sc<46>(vb, c1w, y0, x0, acc0, acc1);
    STORE_TILE(t1, 44, -6)
  }
  __syncthreads();

  // c2: t1(44) -> t2(42), out origin gy0-5
  if (tid < 441){
    int qy=tid/21, qx=tid-qy*21, y0=2*qy, x0=2*qx;
    v2f acc0[4], acc1[4];
    #pragma unroll
    for (int co=0;co<4;++co){ float bv=c2b[co]; acc0[co]=mkv2(bv,bv); acc1[co]=acc0[co]; }
    ACC4_NHWC(t1, 44, c2w, 4, 0, y0, x0, false)
    STORE_TILE(t2, 42, -5)
  }
  __syncthreads();

  // c3: t2(42) -> t3(40), out origin gy0-4
  if (tid < 400){
    int qy=tid/20, qx=tid-qy*20, y0=2*qy, x0=2*qx;
    v2f acc0[4], acc1[4];
    #pragma unroll
    for (int co=0;co<4;++co){ float bv=c3b[co]; acc0[co]=mkv2(bv,bv); acc1[co]=acc0[co]; }
    ACC4_NHWC(t2, 42, c3w, 4, 0, y0, x0, false)
    STORE_TILE(t3, 40, -4)
  }
  __syncthreads();

  // c4: t3(40) -> t4(38), out origin gy0-3
  if (tid < 361){
    int qy=tid/19, qx=tid-qy*19, y0=2*qy, x0=2*qx;
    v2f acc0[4], acc1[4];
    #pragma unroll
    for (int co=0;co<4;++co){ float bv=c4b[co]; acc0[co]=mkv2(bv,bv); acc1[co]=acc0[co]; }
    ACC4_NHWC(t3, 40, c4w, 4, 0, y0, x0, false)
    STORE_TILE(t4, 38, -3)
  }
  __syncthreads();

  // c5: concat(t3@(+1,+1) odd, t4) -> t5(36), out origin gy0-2
  if (tid < 324){
    int qy=tid/18, qx=tid-qy*18, y0=2*qy, x0=2*qx;
    v2f acc0[4], acc1[4];
    #pragma unroll
    for (int co=0;co<4;++co){ float bv=c5b[co]; acc0[co]=mkv2(bv,bv); acc1[co]=acc0[co]; }
    ACC4_NHWC(t3, 40, c5w, 8, 0, y0+1, x0+1, true)
    ACC4_NHWC(t4, 38, c5w, 8, 4, y0,   x0,   false)
    STORE_TILE(t5, 36, -2)
  }
  __syncthreads();

  // c6: concat(t2@(+3,+3) odd, t5) -> t6(34), out origin gy0-1
  if (tid < 289){
    int qy=tid/17, qx=tid-qy*17, y0=2*qy, x0=2*qx;
    v2f acc0[4], acc1[4];
    #pragma unroll
    for (int co=0;co<4;++co){ float bv=c6b[co]; acc0[co]=mkv2(bv,bv); acc1[co]=acc0[co]; }
    ACC4_NHWC(t2, 42, c6w, 8, 0, y0+3, x0+3, true)
    ACC4_NHWC(t5, 36, c6w, 8, 4, y0,   x0,   false)
    STORE_TILE(t6, 34, -1)
  }
  __syncthreads();

  // c7: concat(t1@(+5,+5) odd, t6) -> sigmoid -> v_r, out origin gy0 (interior)
  if (tid < 256){
    int qy=tid>>4, qx=tid&15, y0=2*qy, x0=2*qx;
    float bv=c7b[0];
    v2f s0=mkv2(bv,bv), s1=s0;
    ACC1_NHWC(t1, 44, c7w, 0, y0+5, x0+5, true)
    ACC1_NHWC(t6, 34, c7w, 4, y0,   x0,   false)
    float* vo = vr + (size_t)b*PLANE;
    *(float2*)&vo[(gy0+y0  )*512 + gx0+x0] =
        make_float2(1.f/(1.f+expf(-s0.x)), 1.f/(1.f+expf(-s0.y)));
    *(float2*)&vo[(gy0+y0+1)*512 + gx0+x0] =
        make_float2(1.f/(1.f+expf(-s1.x)), 1.f/(1.f+expf(-s1.y)));
  }
}

// ---------------- subsample + m-conv(stride2) + leaky + instance norm -> src(S,B,E) ----------------
__launch_bounds__(256)
__global__ void k_mnorm(const float* __restrict__ xg, const float* __restrict__ mw,
                        const float* __restrict__ mb, const float* __restrict__ ing,
                        const float* __restrict__ inb, float* __restrict__ src){
  int bc = blockIdx.x;           // 128 = b*16+c
  int b = bc >> 4, c = bc & 15;
  int tid = threadIdx.x;         // 256 = out pixel (i*16+j)
  int i = tid >> 4, j = tid & 15;
  const float* xp = xg + (size_t)b*3*PLANE;
  float s = mb[c];
  #pragma unroll
  for (int dy=0; dy<3; ++dy){
    int ii = 2*i - 1 + dy;
    if ((unsigned)ii >= 32u) continue;
    #pragma unroll
    for (int dx=0; dx<3; ++dx){
      int jj = 2*j - 1 + dx;
      if ((unsigned)jj >= 32u) continue;
      int off = (ii*16)*W + jj*16;
      float vv = (xp[off] + xp[PLANE+off] + xp[2*PLANE+off]) * (1.f/3.f);
      s += vv * mw[c*9 + dy*3 + dx];
    }
  }
  float h = (s >= 0.f) ? s : 0.2f*s;
  __shared__ float red[256];
  red[tid] = h; __syncthreads();
  for (int off=128; off; off>>=1){ if (tid<off) red[tid]+=red[tid+off]; __syncthreads(); }
  float mu = red[0] * (1.f/256.f);
  __syncthreads();
  float d = h - mu;
  red[tid] = d*d; __syncthreads();
  for (int off=128; off; off>>=1){ if (tid<off) red[tid]+=red[tid+off]; __syncthreads(); }
  float var = red[0] * (1.f/256.f);
  float yv = d * rsqrtf(var + 1e-5f) * ing[c] + inb[c];
  src[(size_t)tid*128 + b*16 + c] = yv;   // src[s][b][e], s=tid
}

// ---------------- qkv projection ----------------
__launch_bounds__(256)
__global__ void k_qkv(const float* __restrict__ src, const float* __restrict__ aw,
                      const float* __restrict__ ab, float* __restrict__ qkv){
  int id = blockIdx.x*256 + threadIdx.x;  // 2048*48 = 98304
  int tok = id / 48, o = id % 48;
  const float* sr = src + tok*16;
  float s = ab[o];
  #pragma unroll
  for (int e=0; e<16; ++e) s += sr[e]*aw[o*16+e];
  qkv[tok*48+o] = s;
}

// ---------------- attention (per b,h block; head dim = 2) ----------------
__launch_bounds__(256)
__global__ void k_attn(const float* __restrict__ qkv, float* __restrict__ obuf){
  int b = blockIdx.x >> 3, hh = blockIdx.x & 7;  // 64 blocks
  int t = threadIdx.x;                           // s index
  __shared__ float kk0[256], kk1[256], vv0[256], vv1[256];
  int tok = t*8 + b;
  const float* qr = qkv + tok*48;
  kk0[t] = qr[16 + hh*2]; kk1[t] = qr[16 + hh*2 + 1];
  vv0[t] = qr[32 + hh*2]; vv1[t] = qr[32 + hh*2 + 1];
  float q0 = qr[hh*2], q1 = qr[hh*2 + 1];
  __syncthreads();
  const float sc = 0.70710678118654752f;  // 1/sqrt(2)
  float m = -1e30f;
  for (int u=0; u<256; ++u){
    float s = (q0*kk0[u] + q1*kk1[u]) * sc;
    m = fmaxf(m, s);
  }
  float l = 0.f, a0 = 0.f, a1 = 0.f;
  for (int u=0; u<256; ++u){
    float s = (q0*kk0[u] + q1*kk1[u]) * sc;
    float p = expf(s - m);
    l += p; a0 += p*vv0[u]; a1 += p*vv1[u];
  }
  float inv = 1.f/l;
  obuf[tok*16 + hh*2]     = a0*inv;
  obuf[tok*16 + hh*2 + 1] = a1*inv;
}

// ---------------- out-proj + residual + layernorm1 (in-place on src) ----------------
__launch_bounds__(256)
__global__ void k_oproj_ln(const float* __restrict__ obuf, const float* __restrict__ ow,
                           const float* __restrict__ obias, const float* __restrict__ g,
                           const float* __restrict__ bb, float* __restrict__ src){
  int tok = blockIdx.x*256 + threadIdx.x;  // 2048
  const float* orow = obuf + tok*16;
  float xv[16];
  #pragma unroll
  for (int e=0; e<16; ++e){
    float s = obias[e];
    #pragma unroll
    for (int f=0; f<16; ++f) s += orow[f]*ow[e*16+f];
    xv[e] = src[tok*16+e] + s;
  }
  float mu = 0.f;
  #pragma unroll
  for (int e=0; e<16; ++e) mu += xv[e];
  mu *= (1.f/16.f);
  float var = 0.f;
  #pragma unroll
  for (int e=0; e<16; ++e){ float d = xv[e]-mu; var += d*d; }
  var *= (1.f/16.f);
  float rs = rsqrtf(var + 1e-5f);
  #pragma unroll
  for (int e=0; e<16; ++e) src[tok*16+e] = (xv[e]-mu)*rs*g[e] + bb[e];
}

// ---------------- FFN + residual + layernorm2 (in-place on src) ----------------
__launch_bounds__(64)
__global__ void k_ffn_ln(float* __restrict__ src, const float* __restrict__ w1,
                         const float* __restrict__ b1, const float* __restrict__ w2,
                         const float* __restrict__ b2, const float* __restrict__ g,
                         const float* __restrict__ bb){
  int tok = blockIdx.x;     // 2048
  int tid = threadIdx.x;    // 64
  __shared__ float srow[16], h1[128], xr[16];
  if (tid < 16) srow[tid] = src[tok*16+tid];
  __syncthreads();
  for (int i = tid; i < 128; i += 64){
    float s = b1[i];
    #pragma unroll
    for (int e=0; e<16; ++e) s += srow[e]*w1[i*16+e];
    h1[i] = fmaxf(s, 0.f);
  }
  __syncthreads();
  if (tid < 16){
    float s = b2[tid];
    for (int j=0; j<128; ++j) s += h1[j]*w2[tid*128+j];
    xr[tid] = srow[tid] + s;
  }
  __syncthreads();
  if (tid < 16){
    float mu = 0.f;
    #pragma unroll
    for (int e=0; e<16; ++e) mu += xr[e];
    mu *= (1.f/16.f);
    float var = 0.f;
    #pragma unroll
    for (int e=0; e<16; ++e){ float d = xr[e]-mu; var += d*d; }
    var *= (1.f/16.f);
    src[tok*16+tid] = (xr[tid]-mu)*rsqrtf(var+1e-5f)*g[tid] + bb[tid];
  }
}

// ---------------- final 16x16 valid conv -> level -> g/bcf scalars ----------------
__launch_bounds__(256)
__global__ void k_level(const float* __restrict__ src, const float* __restrict__ fw,
                        const float* __restrict__ fb, float* __restrict__ gb){
  int b = blockIdx.x >> 1, k = blockIdx.x & 1;  // 16 blocks
  int tid = threadIdx.x;                        // s pixel
  float s = 0.f;
  #pragma unroll
  for (int c=0; c<16; ++c)
    s += src[(size_t)tid*128 + b*16 + c] * fw[(k*16+c)*256 + tid];
  __shared__ float red[256];
  red[tid] = s; __syncthreads();
  for (int off=128; off; off>>=1){ if (tid<off) red[tid]+=red[tid+off]; __syncthreads(); }
  if (tid == 0){
    float lev = 1.f/(1.f + expf(-(red[0] + fb[k])));
    gb[b*2+k] = (k==0) ? (0.1f*lev + 0.2f) : (0.04f*lev + 0.06f);
  }
}

// ---------------- final elementwise: enhance + t ----------------
__launch_bounds__(256)
__global__ void k_final(const float* __restrict__ x, const float* __restrict__ gb,
                        float* __restrict__ out){
  int id = blockIdx.x*256 + threadIdx.x;  // 524288
  int b = id >> 16, p = id & 65535;
  const float4* xr = (const float4*)(x + (size_t)(b*3+0)*PLANE);
  const float4* xg = (const float4*)(x + (size_t)(b*3+1)*PLANE);
  const float4* xb = (const float4*)(x + (size_t)(b*3+2)*PLANE);
  const float4* vrp = (const float4*)(out + 6291456 + (size_t)b*PLANE);
  float4 R = xr[p], G = xg[p], Bl = xb[p], VR = vrp[p];
  float gg = gb[b*2+0], bc = gb[b*2+1];
  float lg = log2f(gg);
  float4 er, eg, eb, tr, tg, tb;
#define COMP(SUF, RF, GF, BF, VRF) {            \
    float vv = (RF + GF + BF)/3.f;              \
    float v0 = fminf(fmaxf(vv, 1e-6f), 0.999999f); \
    float r0 = exp2f(VRF * lg);                 \
    float ev0 = exp2f(r0 * log2f(v0));          \
    float d = bc - vv;                          \
    float L = 400.f*d*d*d;                      \
    L = (L < 1e-5f) ? 1e-6f : L;                \
    float fac = (ev0 - L) / (vv + 1e-6f);       \
    er.SUF = RF*fac; eg.SUF = GF*fac; eb.SUF = BF*fac; \
    bool z = vv > 0.04f;                        \
    tr.SUF = z ? 0.f : er.SUF; tg.SUF = z ? 0.f : eg.SUF; tb.SUF = z ? 0.f : eb.SUF; }
  COMP(x, R.x, G.x, Bl.x, VR.x)
  COMP(y, R.y, G.y, Bl.y, VR.y)
  COMP(z, R.z, G.z, Bl.z, VR.z)
  COMP(w, R.w, G.w, Bl.w, VR.w)
#undef COMP
  float4* oe = (float4*)out;
  float4* ot = (float4*)(out + 8388608);
  oe[(size_t)(b*3+0)*PLANE4 + p] = er;
  oe[(size_t)(b*3+1)*PLANE4 + p] = eg;
  oe[(size_t)(b*3+2)*PLANE4 + p] = eb;
  ot[(size_t)(b*3+0)*PLANE4 + p] = tr;
  ot[(size_t)(b*3+1)*PLANE4 + p] = tg;
  ot[(size_t)(b*3+2)*PLANE4 + p] = tb;
}

extern "C" void kernel_launch(void* const* d_in, const int* in_sizes, int n_in,
                              void* d_out, int out_size, void* d_ws, size_t ws_size,
                              hipStream_t stream) {
  const float* x    = (const float*)d_in[0];
  const float* c1w  = (const float*)d_in[1];  const float* c1b = (const float*)d_in[2];
  const float* c2w  = (const float*)d_in[3];  const float* c2b = (const float*)d_in[4];
  const float* c3w  = (const float*)d_in[5];  const float* c3b = (const float*)d_in[6];
  const float* c4w  = (const float*)d_in[7];  const float* c4b = (const float*)d_in[8];
  const float* c5w  = (const float*)d_in[9];  const float* c5b = (const float*)d_in[10];
  const float* c6w  = (const float*)d_in[11]; const float* c6b = (const float*)d_in[12];
  const float* c7w  = (const float*)d_in[13]; const float* c7b = (const float*)d_in[14];
  const float* mw   = (const float*)d_in[15]; const float* mb  = (const float*)d_in[16];
  const float* ing  = (const float*)d_in[17]; const float* inb = (const float*)d_in[18];
  const float* aw   = (const float*)d_in[19]; const float* ab  = (const float*)d_in[20];
  const float* ow   = (const float*)d_in[21]; const float* ob  = (const float*)d_in[22];
  const float* l1w  = (const float*)d_in[23]; const float* l1b = (const float*)d_in[24];
  const float* l2w  = (const float*)d_in[25]; const float* l2b = (const float*)d_in[26];
  const float* n1g  = (const float*)d_in[27]; const float* n1b = (const float*)d_in[28];
  const float* n2g  = (const float*)d_in[29]; const float* n2b = (const float*)d_in[30];
  const float* fw   = (const float*)d_in[31]; const float* fb  = (const float*)d_in[32];

  float* smallws = (float*)d_ws;
  float* src  = smallws;               // 32,768
  float* qkv  = src + 32768;           // 98,304
  float* obuf = qkv + 98304;           // 32,768
  float* gb   = obuf+ 32768;           // 16
  float* out  = (float*)d_out;
  float* vr   = out + 6291456;         // v_r output region

  k_megaconv<<<2048,512,0,stream>>>(x, c1w,c1b, c2w,c2b, c3w,c3b, c4w,c4b,
                                    c5w,c5b, c6w,c6b, c7w,c7b, vr);
  k_mnorm<<<128,256,0,stream>>>(x, mw, mb, ing, inb, src);
  k_qkv<<<384,256,0,stream>>>(src, aw, ab, qkv);
  k_attn<<<64,256,0,stream>>>(qkv, obuf);
  k_oproj_ln<<<8,256,0,stream>>>(obuf, ow, ob, n1g, n1b, src);
  k_ffn_ln<<<2048,64,0,stream>>>(src, l1w, l1b, l2w, l2b, n2g, n2b);
  k_level<<<16,256,0,stream>>>(src, fw, fb, gb);
  k_final<<<2048,256,0,stream>>>(x, gb, out);
}

// Round 10
// 293.710 us; speedup vs baseline: 2.2404x; 2.2404x over previous
//
#include <hip/hip_runtime.h>
#include <math.h>

#define H 512
#define W 512
#define PLANE (H*W)       // 262144
#define PLANE4 (PLANE/4)  // 65536

typedef float v2f __attribute__((ext_vector_type(2)));
typedef unsigned int uint;
typedef unsigned short ushort;

__device__ __forceinline__ float bflo(uint u){ return __uint_as_float(u<<16); }
__device__ __forceinline__ float bfhi(uint u){ return __uint_as_float(u & 0xFFFF0000u); }
__device__ __forceinline__ uint bfpack(float f0, float f1){
  uint a = __float_as_uint(f0), b = __float_as_uint(f1);
  return ((a + 0x8000u) >> 16) | ((b + 0x8000u) & 0xFFFF0000u);
}
__device__ __forceinline__ v2f mkv2(float a, float b){ v2f r; r.x=a; r.y=b; return r; }

// ---- unpack one NHWC row window of 4 pixels (XB even) into P[pixel][ch] ----
#define UNPACK_ROW(P, TL, S, ROWIDX, XB) { \
  uint4 U0 = *(const uint4*)&(TL)[(((ROWIDX))*(S)+(XB))*4]; \
  uint4 U1 = *(const uint4*)&(TL)[(((ROWIDX))*(S)+(XB)+2)*4]; \
  P[0][0]=bflo(U0.x); P[0][1]=bfhi(U0.x); P[0][2]=bflo(U0.y); P[0][3]=bfhi(U0.y); \
  P[1][0]=bflo(U0.z); P[1][1]=bfhi(U0.z); P[1][2]=bflo(U0.w); P[1][3]=bfhi(U0.w); \
  P[2][0]=bflo(U1.x); P[2][1]=bfhi(U1.x); P[2][2]=bflo(U1.y); P[2][3]=bfhi(U1.y); \
  P[3][0]=bflo(U1.z); P[3][1]=bfhi(U1.z); P[3][2]=bflo(U1.w); P[3][3]=bfhi(U1.w); }

// XB odd: pixels XB..XB+3 via three aligned uint4 (XB-1 even)
#define UNPACK_ROW_ODD(P, TL, S, ROWIDX, XB) { \
  uint4 U0 = *(const uint4*)&(TL)[(((ROWIDX))*(S)+(XB)-1)*4]; \
  uint4 U1 = *(const uint4*)&(TL)[(((ROWIDX))*(S)+(XB)+1)*4]; \
  uint4 U2 = *(const uint4*)&(TL)[(((ROWIDX))*(S)+(XB)+3)*4]; \
  P[0][0]=bflo(U0.z); P[0][1]=bfhi(U0.z); P[0][2]=bflo(U0.w); P[0][3]=bfhi(U0.w); \
  P[1][0]=bflo(U1.x); P[1][1]=bfhi(U1.x); P[1][2]=bflo(U1.y); P[1][3]=bfhi(U1.y); \
  P[2][0]=bflo(U1.z); P[2][1]=bfhi(U1.z); P[2][2]=bflo(U1.w); P[2][3]=bfhi(U1.w); \
  P[3][0]=bflo(U2.x); P[3][1]=bfhi(U2.x); P[3][2]=bflo(U2.y); P[3][3]=bfhi(U2.y); }

// one dy slice, 4 ci x 4 co, packed pairs. RL=top rows, RH=bottom rows.
#define DY4(RL, RH, Wb, INC, CIB, DYI) { \
  _Pragma("unroll") \
  for (int ci=0;ci<4;++ci){ \
    v2f A0=mkv2(RL[0][ci],RL[1][ci]), M0=mkv2(RL[1][ci],RL[2][ci]), B0=mkv2(RL[2][ci],RL[3][ci]); \
    v2f A1=mkv2(RH[0][ci],RH[1][ci]), M1=mkv2(RH[1][ci],RH[2][ci]), B1=mkv2(RH[2][ci],RH[3][ci]); \
    _Pragma("unroll") \
    for (int co=0;co<4;++co){ \
      const float* wp = (Wb) + ((co*(INC))+(CIB)+ci)*9 + (DYI)*3; \
      float w0=wp[0], w1=wp[1], w2=wp[2]; \
      acc0[co]+=A0*w0; acc0[co]+=M0*w1; acc0[co]+=B0*w2; \
      acc1[co]+=A1*w0; acc1[co]+=M1*w1; acc1[co]+=B1*w2; \
    } } }

#define ACC4_NHWC(TL, S, Wb, INC, CIB, YB, XB, ODDF) { \
  float r0_[4][4], r1_[4][4], r2_[4][4], r3_[4][4]; \
  if (ODDF){ UNPACK_ROW_ODD(r0_,TL,S,(YB)+0,XB) UNPACK_ROW_ODD(r1_,TL,S,(YB)+1,XB) } \
  else     { UNPACK_ROW(r0_,TL,S,(YB)+0,XB)     UNPACK_ROW(r1_,TL,S,(YB)+1,XB) } \
  DY4(r0_, r1_, Wb, INC, CIB, 0) \
  if (ODDF){ UNPACK_ROW_ODD(r2_,TL,S,(YB)+2,XB) } else { UNPACK_ROW(r2_,TL,S,(YB)+2,XB) } \
  DY4(r1_, r2_, Wb, INC, CIB, 1) \
  if (ODDF){ UNPACK_ROW_ODD(r3_,TL,S,(YB)+3,XB) } else { UNPACK_ROW(r3_,TL,S,(YB)+3,XB) } \
  DY4(r2_, r3_, Wb, INC, CIB, 2) }

// single-output-channel (c7)
#define DY1(RL, RH, Wb, CIB, DYI) { \
  _Pragma("unroll") \
  for (int ci=0;ci<4;++ci){ \
    v2f A0=mkv2(RL[0][ci],RL[1][ci]), M0=mkv2(RL[1][ci],RL[2][ci]), B0=mkv2(RL[2][ci],RL[3][ci]); \
    v2f A1=mkv2(RH[0][ci],RH[1][ci]), M1=mkv2(RH[1][ci],RH[2][ci]), B1=mkv2(RH[2][ci],RH[3][ci]); \
    const float* wp=(Wb)+((CIB)+ci)*9+(DYI)*3; \
    float w0=wp[0],w1=wp[1],w2=wp[2]; \
    s0+=A0*w0; s0+=M0*w1; s0+=B0*w2; \
    s1+=A1*w0; s1+=M1*w1; s1+=B1*w2; } }

#define ACC1_NHWC(TL, S, Wb, CIB, YB, XB, ODDF) { \
  float r0_[4][4], r1_[4][4], r2_[4][4], r3_[4][4]; \
  if (ODDF){ UNPACK_ROW_ODD(r0_,TL,S,(YB)+0,XB) UNPACK_ROW_ODD(r1_,TL,S,(YB)+1,XB) } \
  else     { UNPACK_ROW(r0_,TL,S,(YB)+0,XB)     UNPACK_ROW(r1_,TL,S,(YB)+1,XB) } \
  DY1(r0_,r1_,Wb,CIB,0) \
  if (ODDF){ UNPACK_ROW_ODD(r2_,TL,S,(YB)+2,XB) } else { UNPACK_ROW(r2_,TL,S,(YB)+2,XB) } \
  DY1(r1_,r2_,Wb,CIB,1) \
  if (ODDF){ UNPACK_ROW_ODD(r3_,TL,S,(YB)+3,XB) } else { UNPACK_ROW(r3_,TL,S,(YB)+3,XB) } \
  DY1(r2_,r3_,Wb,CIB,2) }

// scalar-plane (v) -> 4 co (c1); XB even, stride S ushorts
template<int S>
__device__ __forceinline__ void accp4sc(const ushort* __restrict__ pl,
    const float* __restrict__ w, int YB, int XB, v2f* acc0, v2f* acc1)
{
  v2f A[4], Mv[4], Bv[4];
  #pragma unroll
  for (int r=0;r<4;++r){
    const ushort* rp = pl + (YB+r)*S + XB;
    uint u0 = *(const uint*)rp;
    uint u1 = *(const uint*)(rp+2);
    float q0=bflo(u0), q1=bfhi(u0), q2=bflo(u1), q3=bfhi(u1);
    A[r]=mkv2(q0,q1); Mv[r]=mkv2(q1,q2); Bv[r]=mkv2(q2,q3);
  }
  #pragma unroll
  for (int dy=0; dy<3; ++dy){
    #pragma unroll
    for (int co=0; co<4; ++co){
      float w0=w[co*9+dy*3+0], w1=w[co*9+dy*3+1], w2=w[co*9+dy*3+2];
      acc0[co] += A[dy]*w0;   acc0[co] += Mv[dy]*w1;   acc0[co] += Bv[dy]*w2;
      acc1[co] += A[dy+1]*w0; acc1[co] += Mv[dy+1]*w1; acc1[co] += Bv[dy+1]*w2;
    }
  }
}

// pack quad accumulators (masked relu) into two NHWC row uint4s
#define PACK_ROWS(RL4, RH4, M00, M01, M10, M11) \
  uint4 RL4, RH4; { \
    float v00[4],v01[4],v10[4],v11[4]; \
    _Pragma("unroll") \
    for (int co=0;co<4;++co){ \
      v00[co]=(M00)?fmaxf(acc0[co].x,0.f):0.f; \
      v01[co]=(M01)?fmaxf(acc0[co].y,0.f):0.f; \
      v10[co]=(M10)?fmaxf(acc1[co].x,0.f):0.f; \
      v11[co]=(M11)?fmaxf(acc1[co].y,0.f):0.f; } \
    RL4.x=bfpack(v00[0],v00[1]); RL4.y=bfpack(v00[2],v00[3]); \
    RL4.z=bfpack(v01[0],v01[1]); RL4.w=bfpack(v01[2],v01[3]); \
    RH4.x=bfpack(v10[0],v10[1]); RH4.y=bfpack(v10[2],v10[3]); \
    RH4.z=bfpack(v11[0],v11[1]); RH4.w=bfpack(v11[2],v11[3]); }

// phase epilogue: mask, relu, pack, store to NHWC LDS tile (stride S)
#define STORE_TILE(TL, S, GOFF) { \
    bool okr0=(unsigned)(gy0+(GOFF)+y0  )<512u; \
    bool okr1=(unsigned)(gy0+(GOFF)+y0+1)<512u; \
    bool okc0=(unsigned)(gx0+(GOFF)+x0  )<512u; \
    bool okc1=(unsigned)(gx0+(GOFF)+x0+1)<512u; \
    PACK_ROWS(rowlo, rowhi, okr0&okc0, okr0&okc1, okr1&okc0, okr1&okc1) \
    *(uint4*)&(TL)[(y0*(S)+x0)*4]=rowlo; \
    *(uint4*)&(TL)[((y0+1)*(S)+x0)*4]=rowhi; }

// ============ fused conv chain: v->x1->x2->x3->x4->x5->x6->v_r, one WG per 32x32 tile ============
// LDS: vb 4232 + t1 15488 + t2 14112 + t3 12800 + t4 11552 + t5 10368 + t6 9248 = 77800 B -> 2 WG/CU
// NOTE launch_bounds arg-2 behaves as min BLOCKS/CU on this compiler:
// (512,2) -> VGPR cap ~128 (measured 108, no spill); (512,4) -> 64 (spills). Keep 2.
__launch_bounds__(512,2)
__global__ void k_megaconv(const float* __restrict__ xg,
    const float* __restrict__ c1w, const float* __restrict__ c1b,
    const float* __restrict__ c2w, const float* __restrict__ c2b,
    const float* __restrict__ c3w, const float* __restrict__ c3b,
    const float* __restrict__ c4w, const float* __restrict__ c4b,
    const float* __restrict__ c5w, const float* __restrict__ c5b,
    const float* __restrict__ c6w, const float* __restrict__ c6b,
    const float* __restrict__ c7w, const float* __restrict__ c7b,
    float* __restrict__ vr)
{
  __shared__ __align__(16) ushort vb[46*46];
  __shared__ __align__(16) ushort t1[44*44*4];
  __shared__ __align__(16) ushort t2[42*42*4];
  __shared__ __align__(16) ushort t3[40*40*4];
  __shared__ __align__(16) ushort t4[38*38*4];
  __shared__ __align__(16) ushort t5[36*36*4];
  __shared__ __align__(16) ushort t6[34*34*4];
  int wg=blockIdx.x, b=wg>>8, t=wg&255, ty=t>>4, tx=t&15;
  int gy0=ty*32, gx0=tx*32, tid=threadIdx.x;
  const float* xp = xg + (size_t)b*3*PLANE;

  // stage v window (origin gy0-7, gx0-7), 46x46, zero outside image
  for (int i=tid;i<46*46;i+=512){
    int rr=i/46, cc=i-rr*46;
    int gy=gy0-7+rr, gx=gx0-7+cc;
    float val=0.f;
    if (((unsigned)gy<512u)&((unsigned)gx<512u)){
      int off=gy*W+gx;
      val=(xp[off]+xp[PLANE+off]+xp[2*PLANE+off])*(1.f/3.f);
    }
    vb[i]=(ushort)((__float_as_uint(val)+0x8000u)>>16);
  }
  __syncthreads();

  // c1: vb(46) -> t1(44), out origin gy0-6
  if (tid < 484){
    int qy=tid/22, qx=tid-qy*22, y0=2*qy, x0=2*qx;
    v2f acc0[4], acc1[4];
    #pragma unroll
    for (int co=0;co<4;++co){ float bv=c1b[co]; acc0[co]=mkv2(bv,bv); acc1[co]=acc0[co]; }
    accp4sc<46>(vb, c1w, y0, x0, acc0, acc1);
    STORE_TILE(t1, 44, -6)
  }
  __syncthreads();

  // c2: t1(44) -> t2(42), out origin gy0-5
  if (tid < 441){
    int qy=tid/21, qx=tid-qy*21, y0=2*qy, x0=2*qx;
    v2f acc0[4], acc1[4];
    #pragma unroll
    for (int co=0;co<4;++co){ float bv=c2b[co]; acc0[co]=mkv2(bv,bv); acc1[co]=acc0[co]; }
    ACC4_NHWC(t1, 44, c2w, 4, 0, y0, x0, false)
    STORE_TILE(t2, 42, -5)
  }
  __syncthreads();

  // c3: t2(42) -> t3(40), out origin gy0-4
  if (tid < 400){
    int qy=tid/20, qx=tid-qy*20, y0=2*qy, x0=2*qx;
    v2f acc0[4], acc1[4];
    #pragma unroll
    for (int co=0;co<4;++co){ float bv=c3b[co]; acc0[co]=mkv2(bv,bv); acc1[co]=acc0[co]; }
    ACC4_NHWC(t2, 42, c3w, 4, 0, y0, x0, false)
    STORE_TILE(t3, 40, -4)
  }
  __syncthreads();

  // c4: t3(40) -> t4(38), out origin gy0-3
  if (tid < 361){
    int qy=tid/19, qx=tid-qy*19, y0=2*qy, x0=2*qx;
    v2f acc0[4], acc1[4];
    #pragma unroll
    for (int co=0;co<4;++co){ float bv=c4b[co]; acc0[co]=mkv2(bv,bv); acc1[co]=acc0[co]; }
    ACC4_NHWC(t3, 40, c4w, 4, 0, y0, x0, false)
    STORE_TILE(t4, 38, -3)
  }
  __syncthreads();

  // c5: concat(t3@(+1,+1) odd, t4) -> t5(36), out origin gy0-2
  if (tid < 324){
    int qy=tid/18, qx=tid-qy*18, y0=2*qy, x0=2*qx;
    v2f acc0[4], acc1[4];
    #pragma unroll
    for (int co=0;co<4;++co){ float bv=c5b[co]; acc0[co]=mkv2(bv,bv); acc1[co]=acc0[co]; }
    ACC4_NHWC(t3, 40, c5w, 8, 0, y0+1, x0+1, true)
    ACC4_NHWC(t4, 38, c5w, 8, 4, y0,   x0,   false)
    STORE_TILE(t5, 36, -2)
  }
  __syncthreads();

  // c6: concat(t2@(+3,+3) odd, t5) -> t6(34), out origin gy0-1
  if (tid < 289){
    int qy=tid/17, qx=tid-qy*17, y0=2*qy, x0=2*qx;
    v2f acc0[4], acc1[4];
    #pragma unroll
    for (int co=0;co<4;++co){ float bv=c6b[co]; acc0[co]=mkv2(bv,bv); acc1[co]=acc0[co]; }
    ACC4_NHWC(t2, 42, c6w, 8, 0, y0+3, x0+3, true)
    ACC4_NHWC(t5, 36, c6w, 8, 4, y0,   x0,   false)
    STORE_TILE(t6, 34, -1)
  }
  __syncthreads();

  // c7: concat(t1@(+5,+5) odd, t6) -> sigmoid -> v_r, out origin gy0 (interior)
  if (tid < 256){
    int qy=tid>>4, qx=tid&15, y0=2*qy, x0=2*qx;
    float bv=c7b[0];
    v2f s0=mkv2(bv,bv), s1=s0;
    ACC1_NHWC(t1, 44, c7w, 0, y0+5, x0+5, true)
    ACC1_NHWC(t6, 34, c7w, 4, y0,   x0,   false)
    float* vo = vr + (size_t)b*PLANE;
    *(float2*)&vo[(gy0+y0  )*512 + gx0+x0] =
        make_float2(1.f/(1.f+expf(-s0.x)), 1.f/(1.f+expf(-s0.y)));
    *(float2*)&vo[(gy0+y0+1)*512 + gx0+x0] =
        make_float2(1.f/(1.f+expf(-s1.x)), 1.f/(1.f+expf(-s1.y)));
  }
}

// ---------------- subsample + m-conv(stride2) + leaky + instance norm -> src(S,B,E) ----------------
__launch_bounds__(256)
__global__ void k_mnorm(const float* __restrict__ xg, const float* __restrict__ mw,
                        const float* __restrict__ mb, const float* __restrict__ ing,
                        const float* __restrict__ inb, float* __restrict__ src){
  int bc = blockIdx.x;           // 128 = b*16+c
  int b = bc >> 4, c = bc & 15;
  int tid = threadIdx.x;         // 256 = out pixel (i*16+j)
  int i = tid >> 4, j = tid & 15;
  const float* xp = xg + (size_t)b*3*PLANE;
  float s = mb[c];
  #pragma unroll
  for (int dy=0; dy<3; ++dy){
    int ii = 2*i - 1 + dy;
    if ((unsigned)ii >= 32u) continue;
    #pragma unroll
    for (int dx=0; dx<3; ++dx){
      int jj = 2*j - 1 + dx;
      if ((unsigned)jj >= 32u) continue;
      int off = (ii*16)*W + jj*16;
      float vv = (xp[off] + xp[PLANE+off] + xp[2*PLANE+off]) * (1.f/3.f);
      s += vv * mw[c*9 + dy*3 + dx];
    }
  }
  float h = (s >= 0.f) ? s : 0.2f*s;
  __shared__ float red[256];
  red[tid] = h; __syncthreads();
  for (int off=128; off; off>>=1){ if (tid<off) red[tid]+=red[tid+off]; __syncthreads(); }
  float mu = red[0] * (1.f/256.f);
  __syncthreads();
  float d = h - mu;
  red[tid] = d*d; __syncthreads();
  for (int off=128; off; off>>=1){ if (tid<off) red[tid]+=red[tid+off]; __syncthreads(); }
  float var = red[0] * (1.f/256.f);
  float yv = d * rsqrtf(var + 1e-5f) * ing[c] + inb[c];
  src[(size_t)tid*128 + b*16 + c] = yv;   // src[s][b][e], s=tid
}

// ---------------- qkv projection ----------------
__launch_bounds__(256)
__global__ void k_qkv(const float* __restrict__ src, const float* __restrict__ aw,
                      const float* __restrict__ ab, float* __restrict__ qkv){
  int id = blockIdx.x*256 + threadIdx.x;  // 2048*48 = 98304
  int tok = id / 48, o = id % 48;
  const float* sr = src + tok*16;
  float s = ab[o];
  #pragma unroll
  for (int e=0; e<16; ++e) s += sr[e]*aw[o*16+e];
  qkv[tok*48+o] = s;
}

// ---------------- attention (per b,h block; head dim = 2) ----------------
__launch_bounds__(256)
__global__ void k_attn(const float* __restrict__ qkv, float* __restrict__ obuf){
  int b = blockIdx.x >> 3, hh = blockIdx.x & 7;  // 64 blocks
  int t = threadIdx.x;                           // s index
  __shared__ float kk0[256], kk1[256], vv0[256], vv1[256];
  int tok = t*8 + b;
  const float* qr = qkv + tok*48;
  kk0[t] = qr[16 + hh*2]; kk1[t] = qr[16 + hh*2 + 1];
  vv0[t] = qr[32 + hh*2]; vv1[t] = qr[32 + hh*2 + 1];
  float q0 = qr[hh*2], q1 = qr[hh*2 + 1];
  __syncthreads();
  const float sc = 0.70710678118654752f;  // 1/sqrt(2)
  float m = -1e30f;
  for (int u=0; u<256; ++u){
    float s = (q0*kk0[u] + q1*kk1[u]) * sc;
    m = fmaxf(m, s);
  }
  float l = 0.f, a0 = 0.f, a1 = 0.f;
  for (int u=0; u<256; ++u){
    float s = (q0*kk0[u] + q1*kk1[u]) * sc;
    float p = expf(s - m);
    l += p; a0 += p*vv0[u]; a1 += p*vv1[u];
  }
  float inv = 1.f/l;
  obuf[tok*16 + hh*2]     = a0*inv;
  obuf[tok*16 + hh*2 + 1] = a1*inv;
}

// ---------------- out-proj + residual + layernorm1 (in-place on src) ----------------
__launch_bounds__(256)
__global__ void k_oproj_ln(const float* __restrict__ obuf, const float* __restrict__ ow,
                           const float* __restrict__ obias, const float* __restrict__ g,
                           const float* __restrict__ bb, float* __restrict__ src){
  int tok = blockIdx.x*256 + threadIdx.x;  // 2048
  const float* orow = obuf + tok*16;
  float xv[16];
  #pragma unroll
  for (int e=0; e<16; ++e){
    float s = obias[e];
    #pragma unroll
    for (int f=0; f<16; ++f) s += orow[f]*ow[e*16+f];
    xv[e] = src[tok*16+e] + s;
  }
  float mu = 0.f;
  #pragma unroll
  for (int e=0; e<16; ++e) mu += xv[e];
  mu *= (1.f/16.f);
  float var = 0.f;
  #pragma unroll
  for (int e=0; e<16; ++e){ float d = xv[e]-mu; var += d*d; }
  var *= (1.f/16.f);
  float rs = rsqrtf(var + 1e-5f);
  #pragma unroll
  for (int e=0; e<16; ++e) src[tok*16+e] = (xv[e]-mu)*rs*g[e] + bb[e];
}

// ---------------- FFN + residual + layernorm2 (in-place on src) ----------------
__launch_bounds__(64)
__global__ void k_ffn_ln(float* __restrict__ src, const float* __restrict__ w1,
                         const float* __restrict__ b1, const float* __restrict__ w2,
                         const float* __restrict__ b2, const float* __restrict__ g,
                         const float* __restrict__ bb){
  int tok = blockIdx.x;     // 2048
  int tid = threadIdx.x;    // 64
  __shared__ float srow[16], h1[128], xr[16];
  if (tid < 16) srow[tid] = src[tok*16+tid];
  __syncthreads();
  for (int i = tid; i < 128; i += 64){
    float s = b1[i];
    #pragma unroll
    for (int e=0; e<16; ++e) s += srow[e]*w1[i*16+e];
    h1[i] = fmaxf(s, 0.f);
  }
  __syncthreads();
  if (tid < 16){
    float s = b2[tid];
    for (int j=0; j<128; ++j) s += h1[j]*w2[tid*128+j];
    xr[tid] = srow[tid] + s;
  }
  __syncthreads();
  if (tid < 16){
    float mu = 0.f;
    #pragma unroll
    for (int e=0; e<16; ++e) mu += xr[e];
    mu *= (1.f/16.f);
    float var = 0.f;
    #pragma unroll
    for (int e=0; e<16; ++e){ float d = xr[e]-mu; var += d*d; }
    var *= (1.f/16.f);
    src[tok*16+tid] = (xr[tid]-mu)*rsqrtf(var+1e-5f)*g[tid] + bb[tid];
  }
}

// ---------------- final 16x16 valid conv -> level -> g/bcf scalars ----------------
__launch_bounds__(256)
__global__ void k_level(const float* __restrict__ src, const float* __restrict__ fw,
                        const float* __restrict__ fb, float* __restrict__ gb){
  int b = blockIdx.x >> 1, k = blockIdx.x & 1;  // 16 blocks
  int tid = threadIdx.x;                        // s pixel
  float s = 0.f;
  #pragma unroll
  for (int c=0; c<16; ++c)
    s += src[(size_t)tid*128 + b*16 + c] * fw[(k*16+c)*256 + tid];
  __shared__ float red[256];
  red[tid] = s; __syncthreads();
  for (int off=128; off; off>>=1){ if (tid<off) red[tid]+=red[tid+off]; __syncthreads(); }
  if (tid == 0){
    float lev = 1.f/(1.f + expf(-(red[0] + fb[k])));
    gb[b*2+k] = (k==0) ? (0.1f*lev + 0.2f) : (0.04f*lev + 0.06f);
  }
}

// ---------------- final elementwise: enhance + t ----------------
__launch_bounds__(256)
__global__ void k_final(const float* __restrict__ x, const float* __restrict__ gb,
                        float* __restrict__ out){
  int id = blockIdx.x*256 + threadIdx.x;  // 524288
  int b = id >> 16, p = id & 65535;
  const float4* xr = (const float4*)(x + (size_t)(b*3+0)*PLANE);
  const float4* xg = (const float4*)(x + (size_t)(b*3+1)*PLANE);
  const float4* xb = (const float4*)(x + (size_t)(b*3+2)*PLANE);
  const float4* vrp = (const float4*)(out + 6291456 + (size_t)b*PLANE);
  float4 R = xr[p], G = xg[p], Bl = xb[p], VR = vrp[p];
  float gg = gb[b*2+0], bc = gb[b*2+1];
  float lg = log2f(gg);
  float4 er, eg, eb, tr, tg, tb;
#define COMP(SUF, RF, GF, BF, VRF) {            \
    float vv = (RF + GF + BF)/3.f;              \
    float v0 = fminf(fmaxf(vv, 1e-6f), 0.999999f); \
    float r0 = exp2f(VRF * lg);                 \
    float ev0 = exp2f(r0 * log2f(v0));          \
    float d = bc - vv;                          \
    float L = 400.f*d*d*d;                      \
    L = (L < 1e-5f) ? 1e-6f : L;                \
    float fac = (ev0 - L) / (vv + 1e-6f);       \
    er.SUF = RF*fac; eg.SUF = GF*fac; eb.SUF = BF*fac; \
    bool z = vv > 0.04f;                        \
    tr.SUF = z ? 0.f : er.SUF; tg.SUF = z ? 0.f : eg.SUF; tb.SUF = z ? 0.f : eb.SUF; }
  COMP(x, R.x, G.x, Bl.x, VR.x)
  COMP(y, R.y, G.y, Bl.y, VR.y)
  COMP(z, R.z, G.z, Bl.z, VR.z)
  COMP(w, R.w, G.w, Bl.w, VR.w)
#undef COMP
  float4* oe = (float4*)out;
  float4* ot = (float4*)(out + 8388608);
  oe[(size_t)(b*3+0)*PLANE4 + p] = er;
  oe[(size_t)(b*3+1)*PLANE4 + p] = eg;
  oe[(size_t)(b*3+2)*PLANE4 + p] = eb;
  ot[(size_t)(b*3+0)*PLANE4 + p] = tr;
  ot[(size_t)(b*3+1)*PLANE4 + p] = tg;
  ot[(size_t)(b*3+2)*PLANE4 + p] = tb;
}

extern "C" void kernel_launch(void* const* d_in, const int* in_sizes, int n_in,
                              void* d_out, int out_size, void* d_ws, size_t ws_size,
                              hipStream_t stream) {
  const float* x    = (const float*)d_in[0];
  const float* c1w  = (const float*)d_in[1];  const float* c1b = (const float*)d_in[2];
  const float* c2w  = (const float*)d_in[3];  const float* c2b = (const float*)d_in[4];
  const float* c3w  = (const float*)d_in[5];  const float* c3b = (const float*)d_in[6];
  const float* c4w  = (const float*)d_in[7];  const float* c4b = (const float*)d_in[8];
  const float* c5w  = (const float*)d_in[9];  const float* c5b = (const float*)d_in[10];
  const float* c6w  = (const float*)d_in[11]; const float* c6b = (const float*)d_in[12];
  const float* c7w  = (const float*)d_in[13]; const float* c7b = (const float*)d_in[14];
  const float* mw   = (const float*)d_in[15]; const float* mb  = (const float*)d_in[16];
  const float* ing  = (const float*)d_in[17]; const float* inb = (const float*)d_in[18];
  const float* aw   = (const float*)d_in[19]; const float* ab  = (const float*)d_in[20];
  const float* ow   = (const float*)d_in[21]; const float* ob  = (const float*)d_in[22];
  const float* l1w  = (const float*)d_in[23]; const float* l1b = (const float*)d_in[24];
  const float* l2w  = (const float*)d_in[25]; const float* l2b = (const float*)d_in[26];
  const float* n1g  = (const float*)d_in[27]; const float* n1b = (const float*)d_in[28];
  const float* n2g  = (const float*)d_in[29]; const float* n2b = (const float*)d_in[30];
  const float* fw   = (const float*)d_in[31]; const float* fb  = (const float*)d_in[32];

  float* smallws = (float*)d_ws;
  float* src  = smallws;               // 32,768
  float* qkv  = src + 32768;           // 98,304
  float* obuf = qkv + 98304;           // 32,768
  float* gb   = obuf+ 32768;           // 16
  float* out  = (float*)d_out;
  float* vr   = out + 6291456;         // v_r output region

  k_megaconv<<<2048,512,0,stream>>>(x, c1w,c1b, c2w,c2b, c3w,c3b, c4w,c4b,
                                    c5w,c5b, c6w,c6b, c7w,c7b, vr);
  k_mnorm<<<128,256,0,stream>>>(x, mw, mb, ing, inb, src);
  k_qkv<<<384,256,0,stream>>>(src, aw, ab, qkv);
  k_attn<<<64,256,0,stream>>>(qkv, obuf);
  k_oproj_ln<<<8,256,0,stream>>>(obuf, ow, ob, n1g, n1b, src);
  k_ffn_ln<<<2048,64,0,stream>>>(src, l1w, l1b, l2w, l2b, n2g, n2b);
  k_level<<<16,256,0,stream>>>(src, fw, fb, gb);
  k_final<<<2048,256,0,stream>>>(x, gb, out);
}

// Round 12
// 167.334 us; speedup vs baseline: 3.9325x; 1.7552x over previous
//
#include <hip/hip_runtime.h>
#include <math.h>

#define H 512
#define W 512
#define PLANE (H*W)       // 262144
#define PLANE4 (PLANE/4)  // 65536

typedef unsigned int uint;
typedef unsigned short ushort;
typedef _Float16 h2 __attribute__((ext_vector_type(2)));

__device__ __forceinline__ h2 bch2(uint u){ return __builtin_bit_cast(h2, u); }
__device__ __forceinline__ uint pkf16(float a, float b){
  return __builtin_bit_cast(uint, __builtin_amdgcn_cvt_pkrtz(a, b));
}

// ---- load 4x4-pixel window (2 ch-pairs per pixel) from f16 NHWC LDS tile ----
#define LOADWIN_EVEN(WIN, TL, S, YB, XB) { \
  _Pragma("unroll") for (int r_=0;r_<4;++r_){ \
    uint4 Ua = *(const uint4*)&(TL)[(((YB)+r_)*(S)+(XB))*4]; \
    uint4 Ub = *(const uint4*)&(TL)[(((YB)+r_)*(S)+(XB)+2)*4]; \
    WIN[r_][0][0]=bch2(Ua.x); WIN[r_][0][1]=bch2(Ua.y); \
    WIN[r_][1][0]=bch2(Ua.z); WIN[r_][1][1]=bch2(Ua.w); \
    WIN[r_][2][0]=bch2(Ub.x); WIN[r_][2][1]=bch2(Ub.y); \
    WIN[r_][3][0]=bch2(Ub.z); WIN[r_][3][1]=bch2(Ub.w); } }

#define LOADWIN_ODD(WIN, TL, S, YB, XB) { \
  _Pragma("unroll") for (int r_=0;r_<4;++r_){ \
    uint2 U0 = *(const uint2*)&(TL)[(((YB)+r_)*(S)+(XB))*4]; \
    uint4 U1 = *(const uint4*)&(TL)[(((YB)+r_)*(S)+(XB)+1)*4]; \
    uint2 U2 = *(const uint2*)&(TL)[(((YB)+r_)*(S)+(XB)+3)*4]; \
    WIN[r_][0][0]=bch2(U0.x); WIN[r_][0][1]=bch2(U0.y); \
    WIN[r_][1][0]=bch2(U1.x); WIN[r_][1][1]=bch2(U1.y); \
    WIN[r_][2][0]=bch2(U1.z); WIN[r_][2][1]=bch2(U1.w); \
    WIN[r_][3][0]=bch2(U2.x); WIN[r_][3][1]=bch2(U2.y); } }

// ---- dot2 accumulate: 4 co, NPWIN ch-pairs of a window, 2x2 quad ----
// packed weight layout: wpk[(co*NPTOT + PBASE + p)*9 + dy*3+dx]
#define DOTACC(WIN, WPK, NPTOT, PBASE, NPWIN) { \
  _Pragma("unroll") for (int p_=0;p_<NPWIN;++p_){ \
    _Pragma("unroll") for (int dy_=0;dy_<3;++dy_){ \
      _Pragma("unroll") for (int dx_=0;dx_<3;++dx_){ \
        h2 aa=WIN[dy_][dx_][p_],   bb=WIN[dy_][dx_+1][p_]; \
        h2 cc=WIN[dy_+1][dx_][p_], dd=WIN[dy_+1][dx_+1][p_]; \
        _Pragma("unroll") for (int co_=0;co_<4;++co_){ \
          h2 wv = bch2((WPK)[((co_*(NPTOT))+(PBASE)+p_)*9+dy_*3+dx_]); \
          a00[co_]=__builtin_amdgcn_fdot2(aa,wv,a00[co_],false); \
          a01[co_]=__builtin_amdgcn_fdot2(bb,wv,a01[co_],false); \
          a10[co_]=__builtin_amdgcn_fdot2(cc,wv,a10[co_],false); \
          a11[co_]=__builtin_amdgcn_fdot2(dd,wv,a11[co_],false); } } } } }

// single output channel (c7): 2 ch-pairs of one window
#define DOTACC1(WIN, WPK, PBASE) { \
  _Pragma("unroll") for (int p_=0;p_<2;++p_){ \
    _Pragma("unroll") for (int dy_=0;dy_<3;++dy_){ \
      _Pragma("unroll") for (int dx_=0;dx_<3;++dx_){ \
        h2 wv = bch2((WPK)[((PBASE)+p_)*9+dy_*3+dx_]); \
        s00=__builtin_amdgcn_fdot2(WIN[dy_][dx_][p_],  wv,s00,false); \
        s01=__builtin_amdgcn_fdot2(WIN[dy_][dx_+1][p_],wv,s01,false); \
        s10=__builtin_amdgcn_fdot2(WIN[dy_+1][dx_][p_],  wv,s10,false); \
        s11=__builtin_amdgcn_fdot2(WIN[dy_+1][dx_+1][p_],wv,s11,false); } } } }

// phase epilogue: mask, relu, pack f16, store 2 NHWC rows (2 px each) to LDS
#define STORE_TILE(TL, S, GOFF) { \
    bool okr0=(unsigned)(gy0+(GOFF)+y0  )<512u; \
    bool okr1=(unsigned)(gy0+(GOFF)+y0+1)<512u; \
    bool okc0=(unsigned)(gx0+(GOFF)+x0  )<512u; \
    bool okc1=(unsigned)(gx0+(GOFF)+x0+1)<512u; \
    float v00[4],v01[4],v10[4],v11[4]; \
    _Pragma("unroll") \
    for (int co_=0;co_<4;++co_){ \
      v00[co_]=(okr0&okc0)?fmaxf(a00[co_],0.f):0.f; \
      v01[co_]=(okr0&okc1)?fmaxf(a01[co_],0.f):0.f; \
      v10[co_]=(okr1&okc0)?fmaxf(a10[co_],0.f):0.f; \
      v11[co_]=(okr1&okc1)?fmaxf(a11[co_],0.f):0.f; } \
    uint4 rowlo, rowhi; \
    rowlo.x=pkf16(v00[0],v00[1]); rowlo.y=pkf16(v00[2],v00[3]); \
    rowlo.z=pkf16(v01[0],v01[1]); rowlo.w=pkf16(v01[2],v01[3]); \
    rowhi.x=pkf16(v10[0],v10[1]); rowhi.y=pkf16(v10[2],v10[3]); \
    rowhi.z=pkf16(v11[0],v11[1]); rowhi.w=pkf16(v11[2],v11[3]); \
    *(uint4*)&(TL)[(y0*(S)+x0)*4]=rowlo; \
    *(uint4*)&(TL)[((y0+1)*(S)+x0)*4]=rowhi; }

// c1: scalar f16 plane -> 4 co, float weights (small: 4.5% of MACs)
template<int S>
__device__ __forceinline__ void accp4sc(const ushort* __restrict__ pl,
    const float* __restrict__ w, int YB, int XB,
    float* a00, float* a01, float* a10, float* a11)
{
  float q[4][4];
  #pragma unroll
  for (int r=0;r<4;++r){
    const ushort* rp = pl + (YB+r)*S + XB;
    h2 p0 = bch2(*(const uint*)rp);
    h2 p1 = bch2(*(const uint*)(rp+2));
    q[r][0]=(float)p0.x; q[r][1]=(float)p0.y; q[r][2]=(float)p1.x; q[r][3]=(float)p1.y;
  }
  #pragma unroll
  for (int dy=0; dy<3; ++dy)
    #pragma unroll
    for (int dx=0; dx<3; ++dx){
      float q00=q[dy][dx], q01=q[dy][dx+1], q10=q[dy+1][dx], q11=q[dy+1][dx+1];
      #pragma unroll
      for (int co=0; co<4; ++co){
        float wv=w[co*9+dy*3+dx];
        a00[co]+=q00*wv; a01[co]+=q01*wv; a10[co]+=q10*wv; a11[co]+=q11*wv;
      }
    }
}

// ---- weight prep: pack c2..c7 weights as f16 ch-pairs into wpk[540] ----
// c2@0(72) c3@72 c4@144 c5@216(144) c6@360(144) c7@504(36)
__global__ void k_wprep(const float* __restrict__ c2w, const float* __restrict__ c3w,
                        const float* __restrict__ c4w, const float* __restrict__ c5w,
                        const float* __restrict__ c6w, const float* __restrict__ c7w,
                        uint* __restrict__ wpk){
  for (int i=threadIdx.x; i<540; i+=512){
    const float* src; int INC, rel;
    if (i<72){src=c2w;INC=4;rel=i;}
    else if (i<144){src=c3w;INC=4;rel=i-72;}
    else if (i<216){src=c4w;INC=4;rel=i-144;}
    else if (i<360){src=c5w;INC=8;rel=i-216;}
    else if (i<504){src=c6w;INC=8;rel=i-360;}
    else {src=c7w;INC=8;rel=i-504;}
    int NP=INC/2;
    int co=rel/(NP*9); int r2=rel-co*NP*9; int p=r2/9; int tap=r2-p*9;
    float f0 = src[(co*INC + 2*p  )*9 + tap];
    float f1 = src[(co*INC + 2*p+1)*9 + tap];
    wpk[i] = pkf16(f0, f1);
  }
}

// ============ fused conv chain: v->x1..x6->v_r, one WG per 32x32 tile ============
// LDS: vb 4232 + t1..t6 = 77800 B -> 2 WG/CU.
// launch_bounds arg-2 acts as min BLOCKS/CU here: (512,2)->VGPR ~108 ok; (512,4)->64 spills.
__launch_bounds__(512,2)
__global__ void k_megaconv(const float* __restrict__ xg,
    const float* __restrict__ c1w, const float* __restrict__ c1b,
    const float* __restrict__ c2b, const float* __restrict__ c3b,
    const float* __restrict__ c4b, const float* __restrict__ c5b,
    const float* __restrict__ c6b, const float* __restrict__ c7b,
    const uint* __restrict__ wpk,
    float* __restrict__ vr)
{
  __shared__ __align__(16) ushort vb[46*46];
  __shared__ __align__(16) ushort t1[44*44*4];
  __shared__ __align__(16) ushort t2[42*42*4];
  __shared__ __align__(16) ushort t3[40*40*4];
  __shared__ __align__(16) ushort t4[38*38*4];
  __shared__ __align__(16) ushort t5[36*36*4];
  __shared__ __align__(16) ushort t6[34*34*4];
  int wg=blockIdx.x, b=wg>>8, t=wg&255, ty=t>>4, tx=t&15;
  int gy0=ty*32, gx0=tx*32, tid=threadIdx.x;
  const float* xp = xg + (size_t)b*3*PLANE;

  // stage v window (origin gy0-7, gx0-7), 46x46, f16, zero outside image
  for (int i=tid;i<46*46;i+=512){
    int rr=i/46, cc=i-rr*46;
    int gy=gy0-7+rr, gx=gx0-7+cc;
    float val=0.f;
    if (((unsigned)gy<512u)&((unsigned)gx<512u)){
      int off=gy*W+gx;
      val=(xp[off]+xp[PLANE+off]+xp[2*PLANE+off])*(1.f/3.f);
    }
    _Float16 hv=(_Float16)val;
    vb[i]=*(ushort*)&hv;
  }
  __syncthreads();

  // c1: vb(46) -> t1(44), out origin gy0-6  (float weights)
  if (tid < 484){
    int qy=tid/22, qx=tid-qy*22, y0=2*qy, x0=2*qx;
    float a00[4],a01[4],a10[4],a11[4];
    #pragma unroll
    for (int co=0;co<4;++co){ float bv=c1b[co]; a00[co]=bv;a01[co]=bv;a10[co]=bv;a11[co]=bv; }
    accp4sc<46>(vb, c1w, y0, x0, a00,a01,a10,a11);
    STORE_TILE(t1, 44, -6)
  }
  __syncthreads();

  // c2: t1(44) -> t2(42), out origin gy0-5
  if (tid < 441){
    int qy=tid/21, qx=tid-qy*21, y0=2*qy, x0=2*qx;
    float a00[4],a01[4],a10[4],a11[4];
    #pragma unroll
    for (int co=0;co<4;++co){ float bv=c2b[co]; a00[co]=bv;a01[co]=bv;a10[co]=bv;a11[co]=bv; }
    h2 win[4][4][2];
    LOADWIN_EVEN(win, t1, 44, y0, x0)
    DOTACC(win, wpk+0, 2, 0, 2)
    STORE_TILE(t2, 42, -5)
  }
  __syncthreads();

  // c3: t2(42) -> t3(40), out origin gy0-4
  if (tid < 400){
    int qy=tid/20, qx=tid-qy*20, y0=2*qy, x0=2*qx;
    float a00[4],a01[4],a10[4],a11[4];
    #pragma unroll
    for (int co=0;co<4;++co){ float bv=c3b[co]; a00[co]=bv;a01[co]=bv;a10[co]=bv;a11[co]=bv; }
    h2 win[4][4][2];
    LOADWIN_EVEN(win, t2, 42, y0, x0)
    DOTACC(win, wpk+72, 2, 0, 2)
    STORE_TILE(t3, 40, -4)
  }
  __syncthreads();

  // c4: t3(40) -> t4(38), out origin gy0-3
  if (tid < 361){
    int qy=tid/19, qx=tid-qy*19, y0=2*qy, x0=2*qx;
    float a00[4],a01[4],a10[4],a11[4];
    #pragma unroll
    for (int co=0;co<4;++co){ float bv=c4b[co]; a00[co]=bv;a01[co]=bv;a10[co]=bv;a11[co]=bv; }
    h2 win[4][4][2];
    LOADWIN_EVEN(win, t3, 40, y0, x0)
    DOTACC(win, wpk+144, 2, 0, 2)
    STORE_TILE(t4, 38, -3)
  }
  __syncthreads();

  // c5: concat(t3@(+1,+1) odd, t4) -> t5(36), out origin gy0-2
  if (tid < 324){
    int qy=tid/18, qx=tid-qy*18, y0=2*qy, x0=2*qx;
    float a00[4],a01[4],a10[4],a11[4];
    #pragma unroll
    for (int co=0;co<4;++co){ float bv=c5b[co]; a00[co]=bv;a01[co]=bv;a10[co]=bv;a11[co]=bv; }
    {
      h2 win[4][4][2];
      LOADWIN_ODD(win, t3, 40, y0+1, x0+1)
      DOTACC(win, wpk+216, 4, 0, 2)
    }
    {
      h2 win[4][4][2];
      LOADWIN_EVEN(win, t4, 38, y0, x0)
      DOTACC(win, wpk+216, 4, 2, 2)
    }
    STORE_TILE(t5, 36, -2)
  }
  __syncthreads();

  // c6: concat(t2@(+3,+3) odd, t5) -> t6(34), out origin gy0-1
  if (tid < 289){
    int qy=tid/17, qx=tid-qy*17, y0=2*qy, x0=2*qx;
    float a00[4],a01[4],a10[4],a11[4];
    #pragma unroll
    for (int co=0;co<4;++co){ float bv=c6b[co]; a00[co]=bv;a01[co]=bv;a10[co]=bv;a11[co]=bv; }
    {
      h2 win[4][4][2];
      LOADWIN_ODD(win, t2, 42, y0+3, x0+3)
      DOTACC(win, wpk+360, 4, 0, 2)
    }
    {
      h2 win[4][4][2];
      LOADWIN_EVEN(win, t5, 36, y0, x0)
      DOTACC(win, wpk+360, 4, 2, 2)
    }
    STORE_TILE(t6, 34, -1)
  }
  __syncthreads();

  // c7: concat(t1@(+5,+5) odd, t6) -> sigmoid -> v_r, out origin gy0 (interior)
  if (tid < 256){
    int qy=tid>>4, qx=tid&15, y0=2*qy, x0=2*qx;
    float bv=c7b[0];
    float s00=bv, s01=bv, s10=bv, s11=bv;
    {
      h2 win[4][4][2];
      LOADWIN_ODD(win, t1, 44, y0+5, x0+5)
      DOTACC1(win, wpk+504, 0)
    }
    {
      h2 win[4][4][2];
      LOADWIN_EVEN(win, t6, 34, y0, x0)
      DOTACC1(win, wpk+504, 2)
    }
    float* vo = vr + (size_t)b*PLANE;
    *(float2*)&vo[(gy0+y0  )*512 + gx0+x0] =
        make_float2(1.f/(1.f+expf(-s00)), 1.f/(1.f+expf(-s01)));
    *(float2*)&vo[(gy0+y0+1)*512 + gx0+x0] =
        make_float2(1.f/(1.f+expf(-s10)), 1.f/(1.f+expf(-s11)));
  }
}

// ---------------- subsample + m-conv(stride2) + leaky + instance norm -> src(S,B,E) ----------------
__launch_bounds__(256)
__global__ void k_mnorm(const float* __restrict__ xg, const float* __restrict__ mw,
                        const float* __restrict__ mb, const float* __restrict__ ing,
                        const float* __restrict__ inb, float* __restrict__ src){
  int bc = blockIdx.x;           // 128 = b*16+c
  int b = bc >> 4, c = bc & 15;
  int tid = threadIdx.x;         // 256 = out pixel (i*16+j)
  int i = tid >> 4, j = tid & 15;
  const float* xp = xg + (size_t)b*3*PLANE;
  float s = mb[c];
  #pragma unroll
  for (int dy=0; dy<3; ++dy){
    int ii = 2*i - 1 + dy;
    if ((unsigned)ii >= 32u) continue;
    #pragma unroll
    for (int dx=0; dx<3; ++dx){
      int jj = 2*j - 1 + dx;
      if ((unsigned)jj >= 32u) continue;
      int off = (ii*16)*W + jj*16;
      float vv = (xp[off] + xp[PLANE+off] + xp[2*PLANE+off]) * (1.f/3.f);
      s += vv * mw[c*9 + dy*3 + dx];
    }
  }
  float h = (s >= 0.f) ? s : 0.2f*s;
  __shared__ float red[256];
  red[tid] = h; __syncthreads();
  for (int off=128; off; off>>=1){ if (tid<off) red[tid]+=red[tid+off]; __syncthreads(); }
  float mu = red[0] * (1.f/256.f);
  __syncthreads();
  float d = h - mu;
  red[tid] = d*d; __syncthreads();
  for (int off=128; off; off>>=1){ if (tid<off) red[tid]+=red[tid+off]; __syncthreads(); }
  float var = red[0] * (1.f/256.f);
  float yv = d * rsqrtf(var + 1e-5f) * ing[c] + inb[c];
  src[(size_t)tid*128 + b*16 + c] = yv;   // src[s][b][e], s=tid
}

// ---------------- qkv projection ----------------
__launch_bounds__(256)
__global__ void k_qkv(const float* __restrict__ src, const float* __restrict__ aw,
                      const float* __restrict__ ab, float* __restrict__ qkv){
  int id = blockIdx.x*256 + threadIdx.x;  // 2048*48 = 98304
  int tok = id / 48, o = id % 48;
  const float* sr = src + tok*16;
  float s = ab[o];
  #pragma unroll
  for (int e=0; e<16; ++e) s += sr[e]*aw[o*16+e];
  qkv[tok*48+o] = s;
}

// ---------------- attention (per b,h block; head dim = 2) ----------------
__launch_bounds__(256)
__global__ void k_attn(const float* __restrict__ qkv, float* __restrict__ obuf){
  int b = blockIdx.x >> 3, hh = blockIdx.x & 7;  // 64 blocks
  int t = threadIdx.x;                           // s index
  __shared__ float kk0[256], kk1[256], vv0[256], vv1[256];
  int tok = t*8 + b;
  const float* qr = qkv + tok*48;
  kk0[t] = qr[16 + hh*2]; kk1[t] = qr[16 + hh*2 + 1];
  vv0[t] = qr[32 + hh*2]; vv1[t] = qr[32 + hh*2 + 1];
  float q0 = qr[hh*2], q1 = qr[hh*2 + 1];
  __syncthreads();
  const float sc = 0.70710678118654752f;  // 1/sqrt(2)
  float m = -1e30f;
  for (int u=0; u<256; ++u){
    float s = (q0*kk0[u] + q1*kk1[u]) * sc;
    m = fmaxf(m, s);
  }
  float l = 0.f, a0 = 0.f, a1 = 0.f;
  for (int u=0; u<256; ++u){
    float s = (q0*kk0[u] + q1*kk1[u]) * sc;
    float p = expf(s - m);
    l += p; a0 += p*vv0[u]; a1 += p*vv1[u];
  }
  float inv = 1.f/l;
  obuf[tok*16 + hh*2]     = a0*inv;
  obuf[tok*16 + hh*2 + 1] = a1*inv;
}

// ---------------- out-proj + residual + layernorm1 (in-place on src) ----------------
__launch_bounds__(256)
__global__ void k_oproj_ln(const float* __restrict__ obuf, const float* __restrict__ ow,
                           const float* __restrict__ obias, const float* __restrict__ g,
                           const float* __restrict__ bb, float* __restrict__ src){
  int tok = blockIdx.x*256 + threadIdx.x;  // 2048
  const float* orow = obuf + tok*16;
  float xv[16];
  #pragma unroll
  for (int e=0; e<16; ++e){
    float s = obias[e];
    #pragma unroll
    for (int f=0; f<16; ++f) s += orow[f]*ow[e*16+f];
    xv[e] = src[tok*16+e] + s;
  }
  float mu = 0.f;
  #pragma unroll
  for (int e=0; e<16; ++e) mu += xv[e];
  mu *= (1.f/16.f);
  float var = 0.f;
  #pragma unroll
  for (int e=0; e<16; ++e){ float d = xv[e]-mu; var += d*d; }
  var *= (1.f/16.f);
  float rs = rsqrtf(var + 1e-5f);
  #pragma unroll
  for (int e=0; e<16; ++e) src[tok*16+e] = (xv[e]-mu)*rs*g[e] + bb[e];
}

// ---------------- FFN + residual + layernorm2 (in-place on src) ----------------
__launch_bounds__(64)
__global__ void k_ffn_ln(float* __restrict__ src, const float* __restrict__ w1,
                         const float* __restrict__ b1, const float* __restrict__ w2,
                         const float* __restrict__ b2, const float* __restrict__ g,
                         const float* __restrict__ bb){
  int tok = blockIdx.x;     // 2048
  int tid = threadIdx.x;    // 64
  __shared__ float srow[16], h1[128], xr[16];
  if (tid < 16) srow[tid] = src[tok*16+tid];
  __syncthreads();
  for (int i = tid; i < 128; i += 64){
    float s = b1[i];
    #pragma unroll
    for (int e=0; e<16; ++e) s += srow[e]*w1[i*16+e];
    h1[i] = fmaxf(s, 0.f);
  }
  __syncthreads();
  if (tid < 16){
    float s = b2[tid];
    for (int j=0; j<128; ++j) s += h1[j]*w2[tid*128+j];
    xr[tid] = srow[tid] + s;
  }
  __syncthreads();
  if (tid < 16){
    float mu = 0.f;
    #pragma unroll
    for (int e=0; e<16; ++e) mu += xr[e];
    mu *= (1.f/16.f);
    float var = 0.f;
    #pragma unroll
    for (int e=0; e<16; ++e){ float d = xr[e]-mu; var += d*d; }
    var *= (1.f/16.f);
    src[tok*16+tid] = (xr[tid]-mu)*rsqrtf(var+1e-5f)*g[tid] + bb[tid];
  }
}

// ---------------- final 16x16 valid conv -> level -> g/bcf scalars ----------------
__launch_bounds__(256)
__global__ void k_level(const float* __restrict__ src, const float* __restrict__ fw,
                        const float* __restrict__ fb, float* __restrict__ gb){
  int b = blockIdx.x >> 1, k = blockIdx.x & 1;  // 16 blocks
  int tid = threadIdx.x;                        // s pixel
  float s = 0.f;
  #pragma unroll
  for (int c=0; c<16; ++c)
    s += src[(size_t)tid*128 + b*16 + c] * fw[(k*16+c)*256 + tid];
  __shared__ float red[256];
  red[tid] = s; __syncthreads();
  for (int off=128; off; off>>=1){ if (tid<off) red[tid]+=red[tid+off]; __syncthreads(); }
  if (tid == 0){
    float lev = 1.f/(1.f + expf(-(red[0] + fb[k])));
    gb[b*2+k] = (k==0) ? (0.1f*lev + 0.2f) : (0.04f*lev + 0.06f);
  }
}

// ---------------- final elementwise: enhance + t ----------------
__launch_bounds__(256)
__global__ void k_final(const float* __restrict__ x, const float* __restrict__ gb,
                        float* __restrict__ out){
  int id = blockIdx.x*256 + threadIdx.x;  // 524288
  int b = id >> 16, p = id & 65535;
  const float4* xr = (const float4*)(x + (size_t)(b*3+0)*PLANE);
  const float4* xg = (const float4*)(x + (size_t)(b*3+1)*PLANE);
  const float4* xb = (const float4*)(x + (size_t)(b*3+2)*PLANE);
  const float4* vrp = (const float4*)(out + 6291456 + (size_t)b*PLANE);
  float4 R = xr[p], G = xg[p], Bl = xb[p], VR = vrp[p];
  float gg = gb[b*2+0], bc = gb[b*2+1];
  float lg = log2f(gg);
  float4 er, eg, eb, tr, tg, tb;
#define COMP(SUF, RF, GF, BF, VRF) {            \
    float vv = (RF + GF + BF)/3.f;              \
    float v0 = fminf(fmaxf(vv, 1e-6f), 0.999999f); \
    float r0 = exp2f(VRF * lg);                 \
    float ev0 = exp2f(r0 * log2f(v0));          \
    float d = bc - vv;                          \
    float L = 400.f*d*d*d;                      \
    L = (L < 1e-5f) ? 1e-6f : L;                \
    float fac = (ev0 - L) / (vv + 1e-6f);       \
    er.SUF = RF*fac; eg.SUF = GF*fac; eb.SUF = BF*fac; \
    bool z = vv > 0.04f;                        \
    tr.SUF = z ? 0.f : er.SUF; tg.SUF = z ? 0.f : eg.SUF; tb.SUF = z ? 0.f : eb.SUF; }
  COMP(x, R.x, G.x, Bl.x, VR.x)
  COMP(y, R.y, G.y, Bl.y, VR.y)
  COMP(z, R.z, G.z, Bl.z, VR.z)
  COMP(w, R.w, G.w, Bl.w, VR.w)
#undef COMP
  float4* oe = (float4*)out;
  float4* ot = (float4*)(out + 8388608);
  oe[(size_t)(b*3+0)*PLANE4 + p] = er;
  oe[(size_t)(b*3+1)*PLANE4 + p] = eg;
  oe[(size_t)(b*3+2)*PLANE4 + p] = eb;
  ot[(size_t)(b*3+0)*PLANE4 + p] = tr;
  ot[(size_t)(b*3+1)*PLANE4 + p] = tg;
  ot[(size_t)(b*3+2)*PLANE4 + p] = tb;
}

extern "C" void kernel_launch(void* const* d_in, const int* in_sizes, int n_in,
                              void* d_out, int out_size, void* d_ws, size_t ws_size,
                              hipStream_t stream) {
  const float* x    = (const float*)d_in[0];
  const float* c1w  = (const float*)d_in[1];  const float* c1b = (const float*)d_in[2];
  const float* c2w  = (const float*)d_in[3];  const float* c2b = (const float*)d_in[4];
  const float* c3w  = (const float*)d_in[5];  const float* c3b = (const float*)d_in[6];
  const float* c4w  = (const float*)d_in[7];  const float* c4b = (const float*)d_in[8];
  const float* c5w  = (const float*)d_in[9];  const float* c5b = (const float*)d_in[10];
  const float* c6w  = (const float*)d_in[11]; const float* c6b = (const float*)d_in[12];
  const float* c7w  = (const float*)d_in[13]; const float* c7b = (const float*)d_in[14];
  const float* mw   = (const float*)d_in[15]; const float* mb  = (const float*)d_in[16];
  const float* ing  = (const float*)d_in[17]; const float* inb = (const float*)d_in[18];
  const float* aw   = (const float*)d_in[19]; const float* ab  = (const float*)d_in[20];
  const float* ow   = (const float*)d_in[21]; const float* ob  = (const float*)d_in[22];
  const float* l1w  = (const float*)d_in[23]; const float* l1b = (const float*)d_in[24];
  const float* l2w  = (const float*)d_in[25]; const float* l2b = (const float*)d_in[26];
  const float* n1g  = (const float*)d_in[27]; const float* n1b = (const float*)d_in[28];
  const float* n2g  = (const float*)d_in[29]; const float* n2b = (const float*)d_in[30];
  const float* fw   = (const float*)d_in[31]; const float* fb  = (const float*)d_in[32];

  uint* wpk = (uint*)d_ws;             // 540 uints
  float* smallws = (float*)(wpk + 1024);
  float* src  = smallws;               // 32,768
  float* qkv  = src + 32768;           // 98,304
  float* obuf = qkv + 98304;           // 32,768
  float* gb   = obuf+ 32768;           // 16
  float* out  = (float*)d_out;
  float* vr   = out + 6291456;         // v_r output region

  k_wprep<<<1,512,0,stream>>>(c2w, c3w, c4w, c5w, c6w, c7w, wpk);
  k_megaconv<<<2048,512,0,stream>>>(x, c1w, c1b, c2b, c3b, c4b, c5b, c6b, c7b,
                                    wpk, vr);
  k_mnorm<<<128,256,0,stream>>>(x, mw, mb, ing, inb, src);
  k_qkv<<<384,256,0,stream>>>(src, aw, ab, qkv);
  k_attn<<<64,256,0,stream>>>(qkv, obuf);
  k_oproj_ln<<<8,256,0,stream>>>(obuf, ow, ob, n1g, n1b, src);
  k_ffn_ln<<<2048,64,0,stream>>>(src, l1w, l1b, l2w, l2b, n2g, n2b);
  k_level<<<16,256,0,stream>>>(src, fw, fb, gb);
  k_final<<<2048,256,0,stream>>>(x, gb, out);
}